// Round 1
// baseline (581.737 us; speedup 1.0000x reference)
//
#include <hip/hip_runtime.h>
#include <math.h>

// Problem constants (from reference file — compile-time fixed)
#define NB   2
#define LQ   13294
#define LEN  13294
#define NROWS (NB*LQ)      // 26588
#define CDIM 256

// GEMM tile config
#define BM 64
#define BN 64
#define BK 16

// C[r][c] = sum_k A[r][k] * B[c][k] + bias[c]
// A: M x 256 row-major, B: Nc x 256 row-major, C: M x Nc row-major.
// Nc must be a multiple of 64 (true: 256 or 128). K fixed = 256.
__global__ __launch_bounds__(256)
void gemm_bias(const float* __restrict__ A, const float* __restrict__ B,
               const float* __restrict__ bias, float* __restrict__ C,
               int M, int Nc) {
    __shared__ float As[BK][BM + 4];
    __shared__ float Bs[BK][BN + 4];
    const int tid  = threadIdx.x;
    const int row0 = blockIdx.y * BM;
    const int col0 = blockIdx.x * BN;
    const int tr = tid >> 4;      // 0..15
    const int tc = tid & 15;      // 0..15
    const int lk = tid & 15;      // k-lane for staging
    const int li = tid >> 4;      // row-lane for staging

    float acc[4][4] = {};

    for (int kt = 0; kt < 256; kt += BK) {
        #pragma unroll
        for (int j = 0; j < 4; ++j) {
            int i  = li + j * 16;          // 0..63
            int gr = row0 + i;
            float av = 0.f;
            if (gr < M) av = A[gr * 256 + kt + lk];
            As[lk][i] = av;
            int bc = col0 + i;             // always < Nc (Nc % 64 == 0)
            Bs[lk][i] = B[bc * 256 + kt + lk];
        }
        __syncthreads();
        #pragma unroll
        for (int k = 0; k < BK; ++k) {
            float4 a4 = *(const float4*)&As[k][tr * 4];
            float4 b4 = *(const float4*)&Bs[k][tc * 4];
            float a[4] = {a4.x, a4.y, a4.z, a4.w};
            float b[4] = {b4.x, b4.y, b4.z, b4.w};
            #pragma unroll
            for (int i = 0; i < 4; ++i)
                #pragma unroll
                for (int j = 0; j < 4; ++j)
                    acc[i][j] += a[i] * b[j];
        }
        __syncthreads();
    }

    #pragma unroll
    for (int i = 0; i < 4; ++i) {
        int gr = row0 + tr * 4 + i;
        if (gr < M) {
            int gc = col0 + tc * 4;
            float4 o;
            o.x = acc[i][0] + bias[gc + 0];
            o.y = acc[i][1] + bias[gc + 1];
            o.z = acc[i][2] + bias[gc + 2];
            o.w = acc[i][3] + bias[gc + 3];
            *(float4*)&C[gr * Nc + gc] = o;
        }
    }
}

// One block per (n,q). 8 groups of 32 lanes: group = head m, lane = channel d.
// Softmax over 16 logits per head (redundant per lane), then 16 bilinear
// samples from value, accumulate attn-weighted into tmp[n,q,m*32+d].
__global__ __launch_bounds__(256)
void msda_sample(const float* __restrict__ value,    // (NB*LEN, 256)
                 const float* __restrict__ refpts,   // (NB*LQ, 4, 2)
                 const float* __restrict__ off,      // (NB*LQ, 256)
                 const float* __restrict__ logits,   // (NB*LQ, 128)
                 float* __restrict__ tmp) {          // (NB*LQ, 256)
    constexpr int Hs[4] = {100, 50, 25, 13};
    constexpr int Ws[4] = {100, 50, 25, 13};
    constexpr int st[4] = {0, 10000, 12500, 13125};

    const int q = blockIdx.x;           // 0..NROWS-1
    const int n = q / LQ;
    const int t = threadIdx.x;
    const int m = t >> 5;               // head 0..7
    const int d = t & 31;               // channel-in-head 0..31

    // softmax weights for this head
    const float* lg = logits + q * 128 + m * 16;
    float w[16];
    float mx = -1e30f;
    #pragma unroll
    for (int i = 0; i < 16; ++i) { w[i] = lg[i]; mx = fmaxf(mx, w[i]); }
    float s = 0.f;
    #pragma unroll
    for (int i = 0; i < 16; ++i) { w[i] = expf(w[i] - mx); s += w[i]; }
    const float inv = 1.f / s;

    const float* offq  = off + q * 256 + m * 32;
    const float* refq  = refpts + q * 8;
    const float* vbase = value + (n * LEN) * 256 + m * 32 + d;

    float acc = 0.f;
    #pragma unroll
    for (int l = 0; l < 4; ++l) {
        const int H = Hs[l], W = Ws[l];
        const float* vl = vbase + st[l] * 256;
        const float rx = refq[l * 2 + 0];
        const float ry = refq[l * 2 + 1];
        #pragma unroll
        for (int p = 0; p < 4; ++p) {
            const float ox = offq[l * 8 + p * 2 + 0];
            const float oy = offq[l * 8 + p * 2 + 1];
            // replicate reference arithmetic order
            const float locx = rx + ox / (float)W;
            const float locy = ry + oy / (float)H;
            const float grx = 2.f * locx - 1.f;
            const float gry = 2.f * locy - 1.f;
            const float gx = ((grx + 1.f) * (float)W - 1.f) * 0.5f;
            const float gy = ((gry + 1.f) * (float)H - 1.f) * 0.5f;
            const float x0f = floorf(gx), y0f = floorf(gy);
            const float fx = gx - x0f, fy = gy - y0f;
            const int x0 = (int)x0f, y0 = (int)y0f;
            const int x1 = x0 + 1, y1 = y0 + 1;

            const int cx0 = min(max(x0, 0), W - 1);
            const int cx1 = min(max(x1, 0), W - 1);
            const int cy0 = min(max(y0, 0), H - 1);
            const int cy1 = min(max(y1, 0), H - 1);
            const bool vx0 = (x0 >= 0) & (x0 < W);
            const bool vx1 = (x1 >= 0) & (x1 < W);
            const bool vy0 = (y0 >= 0) & (y0 < H);
            const bool vy1 = (y1 >= 0) & (y1 < H);

            float s00 = vl[(cy0 * W + cx0) * 256];
            float s01 = vl[(cy0 * W + cx1) * 256];
            float s10 = vl[(cy1 * W + cx0) * 256];
            float s11 = vl[(cy1 * W + cx1) * 256];
            s00 = (vy0 & vx0) ? s00 : 0.f;
            s01 = (vy0 & vx1) ? s01 : 0.f;
            s10 = (vy1 & vx0) ? s10 : 0.f;
            s11 = (vy1 & vx1) ? s11 : 0.f;

            const float aw = w[l * 4 + p] * inv;
            acc += aw * (s00 * (1.f - fy) * (1.f - fx) +
                         s01 * (1.f - fy) * fx +
                         s10 * fy * (1.f - fx) +
                         s11 * fy * fx);
        }
    }
    tmp[q * 256 + t] = acc;
}

extern "C" void kernel_launch(void* const* d_in, const int* in_sizes, int n_in,
                              void* d_out, int out_size, void* d_ws, size_t ws_size,
                              hipStream_t stream) {
    const float* query  = (const float*)d_in[0];
    const float* refpts = (const float*)d_in[1];
    const float* inflat = (const float*)d_in[2];
    // d_in[3] (shapes), d_in[4] (starts): compile-time constants, unused
    const float* Wv   = (const float*)d_in[5];
    const float* bv   = (const float*)d_in[6];
    const float* Woff = (const float*)d_in[7];
    const float* boff = (const float*)d_in[8];
    const float* Wa   = (const float*)d_in[9];
    const float* ba   = (const float*)d_in[10];
    const float* Wo   = (const float*)d_in[11];
    const float* bo   = (const float*)d_in[12];
    float* out = (float*)d_out;

    float* ws    = (float*)d_ws;
    float* value = ws;                          // NROWS*256 = 6,806,528
    float* offb  = value + (size_t)NROWS * 256;
    float* logit = offb + (size_t)NROWS * 256;  // NROWS*128
    float* tmp   = logit + (size_t)NROWS * 128;

    dim3 blk(256);
    dim3 gFull(CDIM / BN, (NROWS + BM - 1) / BM);   // (4, 416)
    dim3 gAttn(128 / BN, (NROWS + BM - 1) / BM);    // (2, 416)

    hipLaunchKernelGGL(gemm_bias, gFull, blk, 0, stream, inflat, Wv, bv, value, NROWS, 256);
    hipLaunchKernelGGL(gemm_bias, gFull, blk, 0, stream, query, Woff, boff, offb, NROWS, 256);
    hipLaunchKernelGGL(gemm_bias, gAttn, blk, 0, stream, query, Wa, ba, logit, NROWS, 128);
    hipLaunchKernelGGL(msda_sample, dim3(NROWS), blk, 0, stream, value, refpts, offb, logit, tmp);
    hipLaunchKernelGGL(gemm_bias, gFull, blk, 0, stream, tmp, Wo, bo, out, NROWS, 256);
}

// Round 2
// 416.382 us; speedup vs baseline: 1.3971x; 1.3971x over previous
//
#include <hip/hip_runtime.h>
#include <math.h>

// Problem constants (from reference file — compile-time fixed)
#define NB   2
#define LQ   13294
#define LEN  13294
#define NROWS (NB*LQ)      // 26588 = 4 * 6647
#define CDIM 256

// GEMM tile config
#define BM 64
#define BN 64
#define BK 16

// C[r][c] = sum_k A[r][k] * B[c][k] + bias[c]
// A: M x 256 row-major, B: Nc x 256 row-major, C: M x Nc row-major.
__global__ __launch_bounds__(256)
void gemm_bias(const float* __restrict__ A, const float* __restrict__ B,
               const float* __restrict__ bias, float* __restrict__ C,
               int M, int Nc) {
    __shared__ float As[BK][BM + 4];
    __shared__ float Bs[BK][BN + 4];
    const int tid  = threadIdx.x;
    const int row0 = blockIdx.y * BM;
    const int col0 = blockIdx.x * BN;
    const int tr = tid >> 4;      // 0..15
    const int tc = tid & 15;      // 0..15
    const int lk = tid & 15;      // k-lane for staging
    const int li = tid >> 4;      // row-lane for staging

    float acc[4][4] = {};

    for (int kt = 0; kt < 256; kt += BK) {
        #pragma unroll
        for (int j = 0; j < 4; ++j) {
            int i  = li + j * 16;          // 0..63
            int gr = row0 + i;
            float av = 0.f;
            if (gr < M) av = A[gr * 256 + kt + lk];
            As[lk][i] = av;
            int bc = col0 + i;             // always < Nc (Nc % 64 == 0)
            Bs[lk][i] = B[bc * 256 + kt + lk];
        }
        __syncthreads();
        #pragma unroll
        for (int k = 0; k < BK; ++k) {
            float4 a4 = *(const float4*)&As[k][tr * 4];
            float4 b4 = *(const float4*)&Bs[k][tc * 4];
            float a[4] = {a4.x, a4.y, a4.z, a4.w};
            float b[4] = {b4.x, b4.y, b4.z, b4.w};
            #pragma unroll
            for (int i = 0; i < 4; ++i)
                #pragma unroll
                for (int j = 0; j < 4; ++j)
                    acc[i][j] += a[i] * b[j];
        }
        __syncthreads();
    }

    #pragma unroll
    for (int i = 0; i < 4; ++i) {
        int gr = row0 + tr * 4 + i;
        if (gr < M) {
            int gc = col0 + tc * 4;
            float4 o;
            o.x = acc[i][0] + bias[gc + 0];
            o.y = acc[i][1] + bias[gc + 1];
            o.z = acc[i][2] + bias[gc + 2];
            o.w = acc[i][3] + bias[gc + 3];
            *(float4*)&C[gr * Nc + gc] = o;
        }
    }
}

// 4 queries per 256-thread block. Per query: 8 heads x 8 lanes; each lane
// handles 4 channels (float4). Softmax + address math redundant over only
// 8 lanes; all value loads are dwordx4.
__global__ __launch_bounds__(256)
void msda_sample(const float* __restrict__ value,    // (NB*LEN, 256)
                 const float* __restrict__ refpts,   // (NB*LQ, 4, 2)
                 const float* __restrict__ off,      // (NB*LQ, 256)
                 const float* __restrict__ logits,   // (NB*LQ, 128)
                 float* __restrict__ tmp) {          // (NB*LQ, 256)
    constexpr int Hs[4] = {100, 50, 25, 13};
    constexpr int Ws[4] = {100, 50, 25, 13};
    constexpr int st[4] = {0, 10000, 12500, 13125};

    const int t  = threadIdx.x;
    const int qi = t >> 6;              // query-in-block 0..3
    const int m  = (t >> 3) & 7;        // head 0..7
    const int e  = t & 7;               // float4 slot 0..7 (channels e*4..e*4+3)
    const int q  = blockIdx.x * 4 + qi; // NROWS = 4*6647 exactly
    const int n  = q / LQ;

    // softmax weights for this head (redundant over 8 lanes)
    const float* lg = logits + q * 128 + m * 16;
    float w[16];
    float mx = -1e30f;
    #pragma unroll
    for (int i = 0; i < 16; ++i) { w[i] = lg[i]; mx = fmaxf(mx, w[i]); }
    float s = 0.f;
    #pragma unroll
    for (int i = 0; i < 16; ++i) { w[i] = expf(w[i] - mx); s += w[i]; }
    const float inv = 1.f / s;

    const float* offq  = off + q * 256 + m * 32;
    const float* refq  = refpts + q * 8;
    const float* vbase = value + (size_t)(n * LEN) * 256 + m * 32 + e * 4;

    float ax = 0.f, ay = 0.f, az = 0.f, aw_ = 0.f;
    #pragma unroll
    for (int l = 0; l < 4; ++l) {
        const int H = Hs[l], W = Ws[l];
        const float* vl = vbase + st[l] * 256;
        const float rx = refq[l * 2 + 0];
        const float ry = refq[l * 2 + 1];
        #pragma unroll
        for (int p = 0; p < 4; ++p) {
            const float ox = offq[l * 8 + p * 2 + 0];
            const float oy = offq[l * 8 + p * 2 + 1];
            // replicate reference arithmetic order
            const float locx = rx + ox / (float)W;
            const float locy = ry + oy / (float)H;
            const float grx = 2.f * locx - 1.f;
            const float gry = 2.f * locy - 1.f;
            const float gx = ((grx + 1.f) * (float)W - 1.f) * 0.5f;
            const float gy = ((gry + 1.f) * (float)H - 1.f) * 0.5f;
            const float x0f = floorf(gx), y0f = floorf(gy);
            const float fx = gx - x0f, fy = gy - y0f;
            const int x0 = (int)x0f, y0 = (int)y0f;
            const int x1 = x0 + 1, y1 = y0 + 1;

            const int cx0 = min(max(x0, 0), W - 1);
            const int cx1 = min(max(x1, 0), W - 1);
            const int cy0 = min(max(y0, 0), H - 1);
            const int cy1 = min(max(y1, 0), H - 1);
            const bool vx0 = (x0 >= 0) & (x0 < W);
            const bool vx1 = (x1 >= 0) & (x1 < W);
            const bool vy0 = (y0 >= 0) & (y0 < H);
            const bool vy1 = (y1 >= 0) & (y1 < H);

            float4 c00 = *(const float4*)&vl[(cy0 * W + cx0) * 256];
            float4 c01 = *(const float4*)&vl[(cy0 * W + cx1) * 256];
            float4 c10 = *(const float4*)&vl[(cy1 * W + cx0) * 256];
            float4 c11 = *(const float4*)&vl[(cy1 * W + cx1) * 256];

            const float aw = w[l * 4 + p] * inv;
            float w00 = (vy0 & vx0) ? aw * (1.f - fy) * (1.f - fx) : 0.f;
            float w01 = (vy0 & vx1) ? aw * (1.f - fy) * fx         : 0.f;
            float w10 = (vy1 & vx0) ? aw * fy * (1.f - fx)         : 0.f;
            float w11 = (vy1 & vx1) ? aw * fy * fx                 : 0.f;

            ax += w00 * c00.x + w01 * c01.x + w10 * c10.x + w11 * c11.x;
            ay += w00 * c00.y + w01 * c01.y + w10 * c10.y + w11 * c11.y;
            az += w00 * c00.z + w01 * c01.z + w10 * c10.z + w11 * c11.z;
            aw_ += w00 * c00.w + w01 * c01.w + w10 * c10.w + w11 * c11.w;
        }
    }
    float4 o = {ax, ay, az, aw_};
    *(float4*)&tmp[q * 256 + m * 32 + e * 4] = o;
}

extern "C" void kernel_launch(void* const* d_in, const int* in_sizes, int n_in,
                              void* d_out, int out_size, void* d_ws, size_t ws_size,
                              hipStream_t stream) {
    const float* query  = (const float*)d_in[0];
    const float* refpts = (const float*)d_in[1];
    const float* inflat = (const float*)d_in[2];
    // d_in[3] (shapes), d_in[4] (starts): compile-time constants, unused
    const float* Wv   = (const float*)d_in[5];
    const float* bv   = (const float*)d_in[6];
    const float* Woff = (const float*)d_in[7];
    const float* boff = (const float*)d_in[8];
    const float* Wa   = (const float*)d_in[9];
    const float* ba   = (const float*)d_in[10];
    const float* Wo   = (const float*)d_in[11];
    const float* bo   = (const float*)d_in[12];
    float* out = (float*)d_out;

    float* ws    = (float*)d_ws;
    float* value = ws;                          // NROWS*256
    float* offb  = value + (size_t)NROWS * 256;
    float* logit = offb + (size_t)NROWS * 256;  // NROWS*128
    float* tmp   = logit + (size_t)NROWS * 128;

    dim3 blk(256);
    dim3 gFull(CDIM / BN, (NROWS + BM - 1) / BM);   // (4, 416)
    dim3 gAttn(128 / BN, (NROWS + BM - 1) / BM);    // (2, 416)

    hipLaunchKernelGGL(gemm_bias, gFull, blk, 0, stream, inflat, Wv, bv, value, NROWS, 256);
    hipLaunchKernelGGL(gemm_bias, gFull, blk, 0, stream, query, Woff, boff, offb, NROWS, 256);
    hipLaunchKernelGGL(gemm_bias, gAttn, blk, 0, stream, query, Wa, ba, logit, NROWS, 128);
    hipLaunchKernelGGL(msda_sample, dim3(NROWS / 4), blk, 0, stream, value, refpts, offb, logit, tmp);
    hipLaunchKernelGGL(gemm_bias, gFull, blk, 0, stream, tmp, Wo, bo, out, NROWS, 256);
}

// Round 3
// 288.217 us; speedup vs baseline: 2.0184x; 1.4447x over previous
//
#include <hip/hip_runtime.h>
#include <math.h>

// Problem constants (compile-time fixed)
#define NB   2
#define LQ   13294
#define NROWS (NB*LQ)      // 26588 = 4*6647 = 128*207 + 92
#define CDIM 256

typedef unsigned short u16;
typedef unsigned int   u32;
typedef short bf16x8 __attribute__((ext_vector_type(8)));
typedef float f32x4  __attribute__((ext_vector_type(4)));

struct alignas(8) U16x4 { u16 x, y, z, w; };

__device__ __forceinline__ u16 f2bf(float f) {   // round-to-nearest-even
    u32 u = __builtin_bit_cast(u32, f);
    u += 0x7FFFu + ((u >> 16) & 1u);
    return (u16)(u >> 16);
}

__device__ __forceinline__ void gload_lds16(const u16* gp, u16* lp) {
    __builtin_amdgcn_global_load_lds(
        (const __attribute__((address_space(1))) void*)gp,
        (__attribute__((address_space(3))) void*)lp, 16, 0, 0);
}

// fp32 -> bf16, 4 elements/thread
__global__ __launch_bounds__(256)
void cvt_bf16(const float4* __restrict__ in, u16* __restrict__ out) {
    int i = blockIdx.x * 256 + threadIdx.x;
    float4 v = in[i];
    U16x4 o{f2bf(v.x), f2bf(v.y), f2bf(v.z), f2bf(v.w)};
    *(U16x4*)&out[(size_t)i * 4] = o;
}

// Convert all 4 weight matrices into one bf16 region:
// [Wv 65536][Woff 65536][Wa 32768][Wo 65536] = 229376 elements
__global__ __launch_bounds__(256)
void prep_weights(const float* __restrict__ Wv, const float* __restrict__ Woff,
                  const float* __restrict__ Wa, const float* __restrict__ Wo,
                  u16* __restrict__ dst) {
    int i = blockIdx.x * 256 + threadIdx.x;
    float v;
    if      (i <  65536) v = Wv[i];
    else if (i < 131072) v = Woff[i - 65536];
    else if (i < 163840) v = Wa[i - 131072];
    else                 v = Wo[i - 163840];
    dst[i] = f2bf(v);
}

// C[r][c] = sum_k A[r][k]*B[c][k] + bias[c], fp32 out.
// A: M x 256 bf16 row-major. B: NCOLS x 256 bf16 row-major. NCOLS % 128 == 0 or 128.
// Block: 256 thr = 4 waves; tile 128(M) x 128(N) (NCOLS=128 -> grid.x=1);
// wave w computes 64x64 at (w>>1, w&1). BK=32, single-buffered LDS,
// global_load_lds width-16 staging (m97 structure).
template<int NCOLS>
__global__ __launch_bounds__(256)
void gemm_mfma(const u16* __restrict__ A, const u16* __restrict__ B,
               const float* __restrict__ bias, float* __restrict__ C, int M) {
    __shared__ u16 As[128 * 32];
    __shared__ u16 Bs[128 * 32];
    const int tid  = threadIdx.x;
    const int wave = tid >> 6;
    const int lane = tid & 63;
    const int wr = (wave >> 1) * 64;
    const int wc = (wave & 1) * 64;
    const int row0 = blockIdx.y * 128;
    const int col0 = blockIdx.x * 128;

    // staging: wave w loads tile rows [w*32, w*32+32) of A and B, two
    // 16-row instructions each. lane i -> row +(i>>2), 16B chunk (i&3).
    const int srow = lane >> 2;
    const int sk   = (lane & 3) * 8;
    const int ar0  = wave * 32;

    int gra0 = min(row0 + ar0 + srow,      M - 1);
    int gra1 = min(row0 + ar0 + 16 + srow, M - 1);
    const u16* gA0 = A + (size_t)gra0 * 256 + sk;
    const u16* gA1 = A + (size_t)gra1 * 256 + sk;
    const u16* gB0 = B + (size_t)(col0 + ar0 + srow) * 256 + sk;
    const u16* gB1 = gB0 + 16 * 256;
    u16* lA0 = &As[ar0 * 32];
    u16* lA1 = &As[(ar0 + 16) * 32];
    u16* lB0 = &Bs[ar0 * 32];
    u16* lB1 = &Bs[(ar0 + 16) * 32];

    // fragment read bases: a-frag row = wr + i*16 + (lane&15), k = (lane>>4)*8
    const u16* fA = &As[(wr + (lane & 15)) * 32 + (lane >> 4) * 8];
    const u16* fB = &Bs[(wc + (lane & 15)) * 32 + (lane >> 4) * 8];

    f32x4 acc[4][4] = {};

    for (int kt = 0; kt < 256; kt += 32) {
        __syncthreads();
        gload_lds16(gA0 + kt, lA0);
        gload_lds16(gA1 + kt, lA1);
        gload_lds16(gB0 + kt, lB0);
        gload_lds16(gB1 + kt, lB1);
        __syncthreads();
        bf16x8 a[4], b[4];
        #pragma unroll
        for (int i = 0; i < 4; ++i) a[i] = *(const bf16x8*)(fA + i * 16 * 32);
        #pragma unroll
        for (int j = 0; j < 4; ++j) b[j] = *(const bf16x8*)(fB + j * 16 * 32);
        #pragma unroll
        for (int i = 0; i < 4; ++i)
            #pragma unroll
            for (int j = 0; j < 4; ++j)
                acc[i][j] = __builtin_amdgcn_mfma_f32_16x16x32_bf16(
                    a[i], b[j], acc[i][j], 0, 0, 0);
    }

    // C/D layout (m89-verified): col = lane&15, row = (lane>>4)*4 + reg
    const int quad4 = (lane >> 4) * 4;
    const int ln16  = lane & 15;
    #pragma unroll
    for (int j = 0; j < 4; ++j) {
        int gc = col0 + wc + j * 16 + ln16;
        float bj = bias[gc];
        #pragma unroll
        for (int i = 0; i < 4; ++i) {
            int gr0 = row0 + wr + i * 16 + quad4;
            #pragma unroll
            for (int r = 0; r < 4; ++r) {
                int gr = gr0 + r;
                if (gr < M) C[(size_t)gr * NCOLS + gc] = acc[i][j][r] + bj;
            }
        }
    }
}

// 4 queries per 256-thread block; 8 lanes (float4 channels) per (q,head).
__global__ __launch_bounds__(256)
void msda_sample(const float* __restrict__ value,    // (NB*LEN, 256) fp32
                 const float* __restrict__ refpts,   // (NB*LQ, 4, 2)
                 const float* __restrict__ off,      // (NB*LQ, 256) fp32
                 const float* __restrict__ logits,   // (NB*LQ, 128) fp32
                 u16* __restrict__ tmp) {            // (NB*LQ, 256) bf16
    constexpr int Hs[4] = {100, 50, 25, 13};
    constexpr int Ws[4] = {100, 50, 25, 13};
    constexpr int st[4] = {0, 10000, 12500, 13125};

    const int t  = threadIdx.x;
    const int qi = t >> 6;
    const int m  = (t >> 3) & 7;
    const int e  = t & 7;
    const int q  = blockIdx.x * 4 + qi;
    const int n  = q / LQ;

    const float* lg = logits + q * 128 + m * 16;
    float w[16];
    float mx = -1e30f;
    #pragma unroll
    for (int i = 0; i < 16; ++i) { w[i] = lg[i]; mx = fmaxf(mx, w[i]); }
    float s = 0.f;
    #pragma unroll
    for (int i = 0; i < 16; ++i) { w[i] = expf(w[i] - mx); s += w[i]; }
    const float inv = 1.f / s;

    const float* offq  = off + q * 256 + m * 32;
    const float* refq  = refpts + q * 8;
    const float* vbase = value + (size_t)(n * LQ) * 256 + m * 32 + e * 4;

    float ax = 0.f, ay = 0.f, az = 0.f, aw_ = 0.f;
    #pragma unroll
    for (int l = 0; l < 4; ++l) {
        const int H = Hs[l], W = Ws[l];
        const float* vl = vbase + (size_t)st[l] * 256;
        const float rx = refq[l * 2 + 0];
        const float ry = refq[l * 2 + 1];
        #pragma unroll
        for (int p = 0; p < 4; ++p) {
            const float ox = offq[l * 8 + p * 2 + 0];
            const float oy = offq[l * 8 + p * 2 + 1];
            const float locx = rx + ox / (float)W;
            const float locy = ry + oy / (float)H;
            const float grx = 2.f * locx - 1.f;
            const float gry = 2.f * locy - 1.f;
            const float gx = ((grx + 1.f) * (float)W - 1.f) * 0.5f;
            const float gy = ((gry + 1.f) * (float)H - 1.f) * 0.5f;
            const float x0f = floorf(gx), y0f = floorf(gy);
            const float fx = gx - x0f, fy = gy - y0f;
            const int x0 = (int)x0f, y0 = (int)y0f;
            const int x1 = x0 + 1, y1 = y0 + 1;

            const int cx0 = min(max(x0, 0), W - 1);
            const int cx1 = min(max(x1, 0), W - 1);
            const int cy0 = min(max(y0, 0), H - 1);
            const int cy1 = min(max(y1, 0), H - 1);
            const bool vx0 = (x0 >= 0) & (x0 < W);
            const bool vx1 = (x1 >= 0) & (x1 < W);
            const bool vy0 = (y0 >= 0) & (y0 < H);
            const bool vy1 = (y1 >= 0) & (y1 < H);

            float4 c00 = *(const float4*)&vl[(size_t)(cy0 * W + cx0) * 256];
            float4 c01 = *(const float4*)&vl[(size_t)(cy0 * W + cx1) * 256];
            float4 c10 = *(const float4*)&vl[(size_t)(cy1 * W + cx0) * 256];
            float4 c11 = *(const float4*)&vl[(size_t)(cy1 * W + cx1) * 256];

            const float aw = w[l * 4 + p] * inv;
            float w00 = (vy0 & vx0) ? aw * (1.f - fy) * (1.f - fx) : 0.f;
            float w01 = (vy0 & vx1) ? aw * (1.f - fy) * fx         : 0.f;
            float w10 = (vy1 & vx0) ? aw * fy * (1.f - fx)         : 0.f;
            float w11 = (vy1 & vx1) ? aw * fy * fx                 : 0.f;

            ax  += w00 * c00.x + w01 * c01.x + w10 * c10.x + w11 * c11.x;
            ay  += w00 * c00.y + w01 * c01.y + w10 * c10.y + w11 * c11.y;
            az  += w00 * c00.z + w01 * c01.z + w10 * c10.z + w11 * c11.z;
            aw_ += w00 * c00.w + w01 * c01.w + w10 * c10.w + w11 * c11.w;
        }
    }
    U16x4 o{f2bf(ax), f2bf(ay), f2bf(az), f2bf(aw_)};
    *(U16x4*)&tmp[(size_t)q * 256 + m * 32 + e * 4] = o;
}

extern "C" void kernel_launch(void* const* d_in, const int* in_sizes, int n_in,
                              void* d_out, int out_size, void* d_ws, size_t ws_size,
                              hipStream_t stream) {
    const float* query  = (const float*)d_in[0];
    const float* refpts = (const float*)d_in[1];
    const float* inflat = (const float*)d_in[2];
    const float* Wv   = (const float*)d_in[5];
    const float* bv   = (const float*)d_in[6];
    const float* Woff = (const float*)d_in[7];
    const float* boff = (const float*)d_in[8];
    const float* Wa   = (const float*)d_in[9];
    const float* ba   = (const float*)d_in[10];
    const float* Wo   = (const float*)d_in[11];
    const float* bo   = (const float*)d_in[12];
    float* out = (float*)d_out;

    // workspace layout (bytes); qb reused as tmp, ib reused as logit
    char* ws = (char*)d_ws;
    constexpr size_t SZ_ACT16 = (size_t)NROWS * 256 * 2;       // 13,613,056
    u16*   qb    = (u16*)(ws);                                  // bf16 query; later tmp
    u16*   ib    = (u16*)(ws + SZ_ACT16);                       // bf16 input; later logit
    float* value = (float*)(ws + 2 * SZ_ACT16);                 // fp32, 27.2 MB
    u16*   wb    = (u16*)(ws + 2 * SZ_ACT16 + (size_t)NROWS * 256 * 4);
    float* offb  = (float*)(ws + 2 * SZ_ACT16 + (size_t)NROWS * 256 * 4 + 229376 * 2);
    float* logit = (float*)ib;   // fp32 NROWS*128 = same bytes as ib
    u16*   tmp   = qb;           // bf16 NROWS*256

    dim3 blk(256);
    hipLaunchKernelGGL(cvt_bf16, dim3(6647), blk, 0, stream, (const float4*)query,  qb);
    hipLaunchKernelGGL(cvt_bf16, dim3(6647), blk, 0, stream, (const float4*)inflat, ib);
    hipLaunchKernelGGL(prep_weights, dim3(896), blk, 0, stream, Wv, Woff, Wa, Wo, wb);

    gemm_mfma<256><<<dim3(2, 208), blk, 0, stream>>>(ib, wb,          bv,   value, NROWS);
    gemm_mfma<256><<<dim3(2, 208), blk, 0, stream>>>(qb, wb + 65536,  boff, offb,  NROWS);
    gemm_mfma<128><<<dim3(1, 208), blk, 0, stream>>>(qb, wb + 131072, ba,   logit, NROWS);

    hipLaunchKernelGGL(msda_sample, dim3(NROWS / 4), blk, 0, stream,
                       value, refpts, offb, logit, tmp);

    gemm_mfma<256><<<dim3(2, 208), blk, 0, stream>>>(tmp, wb + 163840, bo, out, NROWS);
}